// Round 16
// baseline (334.589 us; speedup 1.0000x reference)
//
#include <hip/hip_runtime.h>
#include <math.h>

#define NU 100000
#define NI 50000
#define NN 150000
#define D 128
#define NE 1000000
#define CD 768
#define BATCH 4096
#define NGEMM 782    // ceil(NI/64)
#define NK (CD / 64) // 12 K-steps of BK=64
#define ABLK_AT 128  // atomic-arm blocks (memory-side bound; few needed)
#define ABLK_XC 192  // xconv-arm blocks
#define ARMTOT (ABLK_AT + ABLK_XC)

typedef short bf16x8 __attribute__((ext_vector_type(8)));
typedef float f32x4 __attribute__((ext_vector_type(4)));

static inline size_t alignup(size_t x, size_t a) { return (x + a - 1) / a * a; }

__device__ inline unsigned short f2bf(float f) {
  unsigned int u = __builtin_bit_cast(unsigned int, f);
  unsigned int r = (u + 0x7fffu + ((u >> 16) & 1u)) >> 16;
  return (unsigned short)r;
}
__device__ inline unsigned int pack2bf(float lo, float hi) {
  return (unsigned int)f2bf(lo) | ((unsigned int)f2bf(hi) << 16);
}
__device__ inline float bflo(unsigned int p) {
  return __builtin_bit_cast(float, p << 16);
}
__device__ inline float bfhi(unsigned int p) {
  return __builtin_bit_cast(float, p & 0xffff0000u);
}

#define ACC8(P, W)                                                        \
  a[0] = fmaf(W, bflo(P.x), a[0]); a[1] = fmaf(W, bfhi(P.x), a[1]);       \
  a[2] = fmaf(W, bflo(P.y), a[2]); a[3] = fmaf(W, bfhi(P.y), a[3]);       \
  a[4] = fmaf(W, bflo(P.z), a[4]); a[5] = fmaf(W, bfhi(P.z), a[5]);       \
  a[6] = fmaf(W, bflo(P.w), a[6]); a[7] = fmaf(W, bfhi(P.w), a[7]);

// 16 lanes per node, lane-sub owns 8 dims; edge record {src, ew}; norm fused inline
__device__ __forceinline__ void gather_rows(
    const int* __restrict__ row_ptr, const uint2* __restrict__ cedge,
    const float* __restrict__ dinv, const uint4* __restrict__ xin,
    int n, int sub, float* a) {
  int beg = row_ptr[n], end = row_ptr[n + 1];
  int j = beg;
  for (; j + 4 <= end; j += 4) {
    uint2 e0 = cedge[j], e1 = cedge[j + 1], e2 = cedge[j + 2], e3 = cedge[j + 3];
    uint4 p0 = xin[(size_t)e0.x * 16 + sub];
    uint4 p1 = xin[(size_t)e1.x * 16 + sub];
    uint4 p2 = xin[(size_t)e2.x * 16 + sub];
    uint4 p3 = xin[(size_t)e3.x * 16 + sub];
    float w0 = dinv[e0.x] * __builtin_bit_cast(float, e0.y);
    float w1 = dinv[e1.x] * __builtin_bit_cast(float, e1.y);
    float w2 = dinv[e2.x] * __builtin_bit_cast(float, e2.y);
    float w3 = dinv[e3.x] * __builtin_bit_cast(float, e3.y);
    ACC8(p0, w0) ACC8(p1, w1) ACC8(p2, w2) ACC8(p3, w3)
  }
  for (; j < end; ++j) {
    uint2 e0 = cedge[j];
    uint4 p0 = xin[(size_t)e0.x * 16 + sub];
    float w0 = dinv[e0.x] * __builtin_bit_cast(float, e0.y);
    ACC8(p0, w0)
  }
}

// ---------------- 3-arm prep: few long-lived arm blocks FIRST, GEMM fills the rest ------------
// blocks [0,128):    edge count + position capture (atomics; memory-side bound)
// blocks [128,320):  x0 bf16 conversion (streaming, grid-stride)
// blocks [320,320+NGEMM): content@W.T GEMM (single-buffer 24KB LDS -> 4 blocks/CU) -> proj
__global__ __launch_bounds__(512) void prep_kernel(
    const int* __restrict__ dst, int* __restrict__ cnt, int* __restrict__ cpos,
    const float* __restrict__ uemb, const float* __restrict__ iemb,
    unsigned int* __restrict__ x0b,
    const float* __restrict__ W, const float* __restrict__ content,
    uint4* __restrict__ proj) {
  __shared__ unsigned short Asm[64 * 64];    // 8 KB
  __shared__ unsigned short Bsm[128 * 64];   // 16 KB (also epilogue transpose buf)

  int bid = blockIdx.x;
  int tid = threadIdx.x;

  if (bid < ABLK_AT) {
    // ---- atomic arm
    int i = bid * 512 + tid;
    for (; i < NE; i += ABLK_AT * 512)
      cpos[i] = atomicAdd(&cnt[dst[i]], 1);
    return;
  }
  if (bid < ARMTOT) {
    // ---- x0 conversion arm
    int half = bid - ABLK_AT;
    const size_t XT = (size_t)NN * D / 8;
    size_t t = (size_t)half * 512 + tid;
    for (; t < XT; t += (size_t)ABLK_XC * 512) {
      size_t f = t * 8;
      const float* p = (f < (size_t)NU * D) ? (uemb + f) : (iemb + (f - (size_t)NU * D));
      float4 a = *(const float4*)p;
      float4 b = *(const float4*)(p + 4);
      uint4 o;
      o.x = pack2bf(a.x, a.y); o.y = pack2bf(a.z, a.w);
      o.z = pack2bf(b.x, b.y); o.w = pack2bf(b.z, b.w);
      *(uint4*)(x0b + t * 4) = o;
    }
    return;
  }
  int slot = bid - ARMTOT;

  // ---- GEMM arm: 64 items x 128 D, BK=64, 12 steps, single-buffered, 8 waves ----
  int w = tid >> 6, lane = tid & 63;
  int i0 = slot * 64;
  int lrow = lane & 15, kq = lane >> 4;

  f32x4 acc[4];
#pragma unroll
  for (int rt = 0; rt < 4; ++rt) acc[rt] = (f32x4){0.f, 0.f, 0.f, 0.f};

  int sr = tid >> 3, c8 = tid & 7;
  int arow_g = (i0 + sr < NI) ? (i0 + sr) : (NI - 1);
  const float* aG = content + (size_t)arow_g * CD + c8 * 8;
  const float* bG0 = W + (size_t)sr * CD + c8 * 8;
  const float* bG1 = W + (size_t)(sr + 64) * CD + c8 * 8;
  int aoff = (c8 * 16) ^ ((sr & 7) << 4);  // same swizzle both B rows ((sr+64)&7 == sr&7)

  // prologue: stage tile 0
  {
    float4 a0 = *(const float4*)(aG);
    float4 a1 = *(const float4*)(aG + 4);
    float4 p0 = *(const float4*)(bG0);
    float4 p1 = *(const float4*)(bG0 + 4);
    float4 q0 = *(const float4*)(bG1);
    float4 q1 = *(const float4*)(bG1 + 4);
    uint4 oa, ob, oc;
    oa.x = pack2bf(a0.x, a0.y); oa.y = pack2bf(a0.z, a0.w);
    oa.z = pack2bf(a1.x, a1.y); oa.w = pack2bf(a1.z, a1.w);
    ob.x = pack2bf(p0.x, p0.y); ob.y = pack2bf(p0.z, p0.w);
    ob.z = pack2bf(p1.x, p1.y); ob.w = pack2bf(p1.z, p1.w);
    oc.x = pack2bf(q0.x, q0.y); oc.y = pack2bf(q0.z, q0.w);
    oc.z = pack2bf(q1.x, q1.y); oc.w = pack2bf(q1.z, q1.w);
    *(uint4*)((char*)Asm + sr * 128 + aoff) = oa;
    *(uint4*)((char*)Bsm + sr * 128 + aoff) = ob;
    *(uint4*)((char*)Bsm + (sr + 64) * 128 + aoff) = oc;
  }
  __syncthreads();

  for (int kk = 0; kk < NK; ++kk) {
    bool more = kk < NK - 1;
    float4 a0, a1, p0, p1, q0, q1;
    if (more) {
      int k0 = (kk + 1) * 64;
      a0 = *(const float4*)(aG + k0);
      a1 = *(const float4*)(aG + k0 + 4);
      p0 = *(const float4*)(bG0 + k0);
      p1 = *(const float4*)(bG0 + k0 + 4);
      q0 = *(const float4*)(bG1 + k0);
      q1 = *(const float4*)(bG1 + k0 + 4);
    }
    // MFMA on current tile
#pragma unroll
    for (int ks = 0; ks < 2; ++ks) {
      int kbyte = ks * 64 + kq * 16;
      bf16x8 af[4], bfr;
#pragma unroll
      for (int rt = 0; rt < 4; ++rt) {
        int row = rt * 16 + lrow;
        af[rt] = *(const bf16x8*)((char*)Asm + row * 128 + (kbyte ^ ((row & 7) << 4)));
      }
      {
        int row = w * 16 + lrow;
        bfr = *(const bf16x8*)((char*)Bsm + row * 128 + (kbyte ^ ((row & 7) << 4)));
      }
#pragma unroll
      for (int rt = 0; rt < 4; ++rt)
        acc[rt] = __builtin_amdgcn_mfma_f32_16x16x32_bf16(af[rt], bfr, acc[rt], 0, 0, 0);
    }
    __syncthreads();  // all reads of the tile complete
    if (more) {
      uint4 oa, ob, oc;
      oa.x = pack2bf(a0.x, a0.y); oa.y = pack2bf(a0.z, a0.w);
      oa.z = pack2bf(a1.x, a1.y); oa.w = pack2bf(a1.z, a1.w);
      ob.x = pack2bf(p0.x, p0.y); ob.y = pack2bf(p0.z, p0.w);
      ob.z = pack2bf(p1.x, p1.y); ob.w = pack2bf(p1.z, p1.w);
      oc.x = pack2bf(q0.x, q0.y); oc.y = pack2bf(q0.z, q0.w);
      oc.z = pack2bf(q1.x, q1.y); oc.w = pack2bf(q1.z, q1.w);
      *(uint4*)((char*)Asm + sr * 128 + aoff) = oa;
      *(uint4*)((char*)Bsm + sr * 128 + aoff) = ob;
      *(uint4*)((char*)Bsm + (sr + 64) * 128 + aoff) = oc;
      __syncthreads();  // staging visible before next reads
    }
  }

  // epilogue: transpose acc through Bsm (16 KB), store proj rows as bf16 uint4
  unsigned short* T = (unsigned short*)Bsm;  // [64][128]
  int dcol = w * 16 + lrow;
#pragma unroll
  for (int rt = 0; rt < 4; ++rt)
#pragma unroll
    for (int j = 0; j < 4; ++j)
      T[(rt * 16 + kq * 4 + j) * 128 + dcol] = f2bf(acc[rt][j]);
  __syncthreads();
#pragma unroll
  for (int u0 = 0; u0 < 2; ++u0) {
    int u = u0 * 512 + tid;
    int r = u >> 4, s = u & 15;
    int it = i0 + r;
    if (it < NI) proj[(size_t)it * 16 + s] = ((const uint4*)T)[u];
  }
}

// ---------------- prefix scan for CSR row_ptr ----------------

__global__ void scan_p1(const int* __restrict__ cnt, int* __restrict__ bsum) {
  __shared__ int s[256];
  int b = blockIdx.x;
  int i = b * 256 + threadIdx.x;
  s[threadIdx.x] = (i < NN) ? cnt[i] : 0;
  __syncthreads();
  for (int off = 128; off; off >>= 1) {
    if (threadIdx.x < off) s[threadIdx.x] += s[threadIdx.x + off];
    __syncthreads();
  }
  if (threadIdx.x == 0) bsum[b] = s[0];
}

__global__ __launch_bounds__(1024) void scan_p2(int* __restrict__ bsum, int nb) {
  __shared__ int s[1024];
  int t = threadIdx.x;
  int v = (t < nb) ? bsum[t] : 0;
  s[t] = v;
  __syncthreads();
  for (int off = 1; off < 1024; off <<= 1) {
    int u = (t >= off) ? s[t - off] : 0;
    __syncthreads();
    s[t] += u;
    __syncthreads();
  }
  if (t < nb) bsum[t] = s[t] - v;
}

__global__ void scan_p3(const int* __restrict__ cnt, const int* __restrict__ bsum,
                        int* __restrict__ row_ptr) {
  __shared__ int s[256];
  int b = blockIdx.x;
  int i = b * 256 + threadIdx.x;
  s[threadIdx.x] = (i < NN) ? cnt[i] : 0;
  __syncthreads();
  for (int off = 1; off < 256; off <<= 1) {
    int t = (threadIdx.x >= off) ? s[threadIdx.x - off] : 0;
    __syncthreads();
    s[threadIdx.x] += t;
    __syncthreads();
  }
  if (i < NN) row_ptr[i + 1] = bsum[b] + s[threadIdx.x];
  if (i == 0) row_ptr[0] = 0;
}

// ---------------- CSR fill: packed edge records {src, ew}, no atomics ----------------
__global__ void fill_kernel(const int* __restrict__ src, const int* __restrict__ dst,
                            const float* __restrict__ ew, const int* __restrict__ row_ptr,
                            const int* __restrict__ cpos, uint2* __restrict__ cedge) {
  int i = blockIdx.x * blockDim.x + threadIdx.x;
  int stride = gridDim.x * blockDim.x;
  for (; i < NE; i += stride) {
    int p = row_ptr[dst[i]] + cpos[i];
    uint2 e;
    e.x = (unsigned int)src[i];
    e.y = __builtin_bit_cast(unsigned int, ew[i]);
    cedge[p] = e;
  }
}

// ---------------- degree from CSR row sums + rsqrt ----------------
__global__ void degrow_kernel(const int* __restrict__ row_ptr, const uint2* __restrict__ cedge,
                              float* __restrict__ dinv) {
  int n = blockIdx.x * blockDim.x + threadIdx.x;
  if (n >= NN) return;
  int beg = row_ptr[n], end = row_ptr[n + 1];
  float s = 0.f;
  for (int p = beg; p < end; ++p) s += __builtin_bit_cast(float, cedge[p].y);
  dinv[n] = (s > 0.f) ? rsqrtf(s) : 0.f;
}

// ---------------- propagation layers (bf16 state; norm fused into gather) ----------------
__global__ __launch_bounds__(256) void gather_kernel(
    const int* __restrict__ row_ptr, const uint2* __restrict__ cedge,
    const float* __restrict__ dinv, const uint4* __restrict__ xin,
    uint4* __restrict__ yout) {
  int tid = threadIdx.x;
  int wv = tid >> 6, lane = tid & 63;
  int g = lane >> 4, sub = lane & 15;
  int n = blockIdx.x * 16 + wv * 4 + g;
  if (n >= NN) return;
  float sc = dinv[n];
  float a[8] = {0.f, 0.f, 0.f, 0.f, 0.f, 0.f, 0.f, 0.f};
  gather_rows(row_ptr, cedge, dinv, xin, n, sub, a);
  uint4 o;
  o.x = pack2bf(a[0] * sc, a[1] * sc);
  o.y = pack2bf(a[2] * sc, a[3] * sc);
  o.z = pack2bf(a[4] * sc, a[5] * sc);
  o.w = pack2bf(a[6] * sc, a[7] * sc);
  yout[(size_t)n * 16 + sub] = o;
}

// final layer: gather y3, OUT = 0.25*(x0+y1+y2+y3), fused align-MSE for item rows
__global__ __launch_bounds__(256) void final_kernel(
    const int* __restrict__ row_ptr, const uint2* __restrict__ cedge,
    const float* __restrict__ dinv, const uint4* __restrict__ x0b,
    const uint4* __restrict__ y1b, const uint4* __restrict__ y2b,
    const uint4* __restrict__ proj, float* __restrict__ OUT,
    float* __restrict__ partials) {
  __shared__ float wred[4];
  int tid = threadIdx.x;
  int wv = tid >> 6, lane = tid & 63;
  int g = lane >> 4, sub = lane & 15;
  int n = blockIdx.x * 16 + wv * 4 + g;
  if (n >= NN) return;
  // hoist independent stream loads before the gather loop (MLP)
  size_t r = (size_t)n * 16 + sub;
  uint4 q0 = x0b[r], q1 = y1b[r], q2 = y2b[r];
  float sc = dinv[n];
  float a[8] = {0.f, 0.f, 0.f, 0.f, 0.f, 0.f, 0.f, 0.f};
  gather_rows(row_ptr, cedge, dinv, y2b, n, sub, a);
  float v[8];
  v[0] = (bflo(q0.x) + bflo(q1.x) + bflo(q2.x) + a[0] * sc) * 0.25f;
  v[1] = (bfhi(q0.x) + bfhi(q1.x) + bfhi(q2.x) + a[1] * sc) * 0.25f;
  v[2] = (bflo(q0.y) + bflo(q1.y) + bflo(q2.y) + a[2] * sc) * 0.25f;
  v[3] = (bfhi(q0.y) + bfhi(q1.y) + bfhi(q2.y) + a[3] * sc) * 0.25f;
  v[4] = (bflo(q0.z) + bflo(q1.z) + bflo(q2.z) + a[4] * sc) * 0.25f;
  v[5] = (bfhi(q0.z) + bfhi(q1.z) + bfhi(q2.z) + a[5] * sc) * 0.25f;
  v[6] = (bflo(q0.w) + bflo(q1.w) + bflo(q2.w) + a[6] * sc) * 0.25f;
  v[7] = (bfhi(q0.w) + bfhi(q1.w) + bfhi(q2.w) + a[7] * sc) * 0.25f;
  float* op = OUT + (size_t)n * D + sub * 8;
#pragma unroll
  for (int k = 0; k < 8; ++k) op[k] = v[k];

  // item blocks are exactly blockIdx.x >= NU/16 (NU divisible by 16)
  if (blockIdx.x >= (NU / 16)) {
    uint4 pj = proj[(size_t)(n - NU) * 16 + sub];
    float d0 = v[0] - bflo(pj.x), d1 = v[1] - bfhi(pj.x);
    float d2 = v[2] - bflo(pj.y), d3 = v[3] - bfhi(pj.y);
    float d4 = v[4] - bflo(pj.z), d5 = v[5] - bfhi(pj.z);
    float d6 = v[6] - bflo(pj.w), d7 = v[7] - bfhi(pj.w);
    float m = d0 * d0 + d1 * d1 + d2 * d2 + d3 * d3 + d4 * d4 + d5 * d5 + d6 * d6 + d7 * d7;
    for (int off = 32; off; off >>= 1) m += __shfl_down(m, off);
    if (lane == 0) wred[wv] = m;
    __syncthreads();
    if (tid == 0)
      atomicAdd(&partials[blockIdx.x & 255], wred[0] + wred[1] + wred[2] + wred[3]);
  }
}

// ---------------- BPR + reg loss over batch (block-reduced atomics) ----------------
__global__ __launch_bounds__(256) void loss_batch(
    const int* __restrict__ bu, const int* __restrict__ bp, const int* __restrict__ bn,
    const float* __restrict__ OUT, float* __restrict__ accums) {
  __shared__ float wsp[4], wrg[4];
  int wv = threadIdx.x >> 6, lane = threadIdx.x & 63;
  int gw = blockIdx.x * 4 + wv;
  int nw = gridDim.x * 4;
  float lsp = 0.f, lrg = 0.f;
  for (int b = gw; b < BATCH; b += nw) {
    const float* u = OUT + (size_t)bu[b] * D;
    const float* ip = OUT + ((size_t)NU + bp[b]) * D;
    const float* in_ = OUT + ((size_t)NU + bn[b]) * D;
    float u0 = u[lane], u1 = u[lane + 64];
    float p0 = ip[lane], p1 = ip[lane + 64];
    float n0 = in_[lane], n1 = in_[lane + 64];
    float ps = u0 * p0 + u1 * p1;
    float ns = u0 * n0 + u1 * n1;
    float rg = u0 * u0 + u1 * u1 + p0 * p0 + p1 * p1 + n0 * n0 + n1 * n1;
    for (int off = 32; off; off >>= 1) {
      ps += __shfl_down(ps, off);
      ns += __shfl_down(ns, off);
      rg += __shfl_down(rg, off);
    }
    if (lane == 0) {
      float x = ns - ps;
      lsp += fmaxf(x, 0.f) + log1pf(expf(-fabsf(x)));
      lrg += rg;
    }
  }
  if (lane == 0) { wsp[wv] = lsp; wrg[wv] = lrg; }
  __syncthreads();
  if (threadIdx.x == 0) {
    atomicAdd(&accums[0], wsp[0] + wsp[1] + wsp[2] + wsp[3]);
    atomicAdd(&accums[1], wrg[0] + wrg[1] + wrg[2] + wrg[3]);
  }
}

__global__ void finalize_kernel(const float* __restrict__ accums,
                                const float* __restrict__ partials,
                                float* __restrict__ out0) {
  __shared__ float sm[4];
  int tid = threadIdx.x;
  float v = partials[tid];
  for (int off = 32; off; off >>= 1) v += __shfl_down(v, off);
  if ((tid & 63) == 0) sm[tid >> 6] = v;
  __syncthreads();
  if (tid == 0) {
    float align_sum = sm[0] + sm[1] + sm[2] + sm[3];
    float bpr = accums[0] / (float)BATCH;
    float reg = (accums[1] / (float)BATCH) * 1e-4f;
    float align = align_sum / (float)((size_t)NI * D);
    out0[0] = bpr + reg + 0.1f * align;
  }
}

// ---------------- launch ----------------
extern "C" void kernel_launch(void* const* d_in, const int* in_sizes, int n_in,
                              void* d_out, int out_size, void* d_ws, size_t ws_size,
                              hipStream_t stream) {
  const int* edge_index = (const int*)d_in[0];
  const float* ew = (const float*)d_in[1];
  const int* bu = (const int*)d_in[2];
  const int* bp = (const int*)d_in[3];
  const int* bn = (const int*)d_in[4];
  const float* content = (const float*)d_in[5];
  const float* uemb = (const float*)d_in[6];
  const float* iemb = (const float*)d_in[7];
  const float* W = (const float*)d_in[8];
  const int* src = edge_index;
  const int* dst = edge_index + NE;
  float* outf = (float*)d_out;
  float* OUT = outf + 1;  // [NN][D] fp32 (4B-aligned only!)

  char* ws = (char*)d_ws;
  size_t off = 0;
  auto alloc = [&](size_t bytes) {
    void* p = ws + off;
    off = alignup(off + bytes, 256);
    return p;
  };
  unsigned int* x0b = (unsigned int*)alloc((size_t)NN * 64 * 4);  // bf16 [NN][128]
  unsigned int* y1b = (unsigned int*)alloc((size_t)NN * 64 * 4);  // bf16 [NN][128]
  unsigned int* y2b = (unsigned int*)alloc((size_t)NN * 64 * 4);  // bf16 [NN][128]
  uint4* proj = (uint4*)alloc((size_t)NI * 16 * 16);              // bf16 [NI][128]
  float* dinv = (float*)alloc((size_t)NN * 4);
  int* cnt = (int*)alloc((size_t)NN * 4);
  int* row_ptr = (int*)alloc((size_t)(NN + 1) * 4);
  int NB = (NN + 255) / 256;
  int* bsum = (int*)alloc((size_t)NB * 4);
  int* cpos = (int*)alloc((size_t)NE * 4);
  uint2* cedge = (uint2*)alloc((size_t)NE * 8);
  float* accums = (float*)alloc(16 + 256 * 4);  // [0..3] accums, [4..259] mse partials
  float* partials = accums + 4;

  hipMemsetAsync(cnt, 0, (size_t)NN * 4, stream);
  hipMemsetAsync(accums, 0, 16 + 256 * 4, stream);

  prep_kernel<<<ARMTOT + NGEMM, 512, 0, stream>>>(dst, cnt, cpos, uemb, iemb, x0b, W, content, proj);
  scan_p1<<<NB, 256, 0, stream>>>(cnt, bsum);
  scan_p2<<<1, 1024, 0, stream>>>(bsum, NB);
  scan_p3<<<NB, 256, 0, stream>>>(cnt, bsum, row_ptr);
  fill_kernel<<<2048, 256, 0, stream>>>(src, dst, ew, row_ptr, cpos, cedge);
  degrow_kernel<<<NB, 256, 0, stream>>>(row_ptr, cedge, dinv);

  int LB = (NN + 15) / 16;
  gather_kernel<<<LB, 256, 0, stream>>>(row_ptr, cedge, dinv, (const uint4*)x0b, (uint4*)y1b);
  gather_kernel<<<LB, 256, 0, stream>>>(row_ptr, cedge, dinv, (const uint4*)y1b, (uint4*)y2b);
  final_kernel<<<LB, 256, 0, stream>>>(row_ptr, cedge, dinv,
                                       (const uint4*)x0b, (const uint4*)y1b, (const uint4*)y2b,
                                       proj, OUT, partials);

  loss_batch<<<64, 256, 0, stream>>>(bu, bp, bn, OUT, accums);
  finalize_kernel<<<1, 256, 0, stream>>>(accums, partials, outf);
}

// Round 17
// 319.107 us; speedup vs baseline: 1.0485x; 1.0485x over previous
//
#include <hip/hip_runtime.h>
#include <math.h>

#define NU 100000
#define NI 50000
#define NN 150000
#define D 128
#define NE 1000000
#define CD 768
#define BATCH 4096
#define NGEMM 782    // ceil(NI/64)
#define NK (CD / 64) // 12 K-steps of BK=64

typedef short bf16x8 __attribute__((ext_vector_type(8)));
typedef float f32x4 __attribute__((ext_vector_type(4)));

static inline size_t alignup(size_t x, size_t a) { return (x + a - 1) / a * a; }

__device__ inline unsigned short f2bf(float f) {
  unsigned int u = __builtin_bit_cast(unsigned int, f);
  unsigned int r = (u + 0x7fffu + ((u >> 16) & 1u)) >> 16;
  return (unsigned short)r;
}
__device__ inline unsigned int pack2bf(float lo, float hi) {
  return (unsigned int)f2bf(lo) | ((unsigned int)f2bf(hi) << 16);
}
__device__ inline float bflo(unsigned int p) {
  return __builtin_bit_cast(float, p << 16);
}
__device__ inline float bfhi(unsigned int p) {
  return __builtin_bit_cast(float, p & 0xffff0000u);
}

#define ACC8(P, W)                                                        \
  a[0] = fmaf(W, bflo(P.x), a[0]); a[1] = fmaf(W, bfhi(P.x), a[1]);       \
  a[2] = fmaf(W, bflo(P.y), a[2]); a[3] = fmaf(W, bfhi(P.y), a[3]);       \
  a[4] = fmaf(W, bflo(P.z), a[4]); a[5] = fmaf(W, bfhi(P.z), a[5]);       \
  a[6] = fmaf(W, bflo(P.w), a[6]); a[7] = fmaf(W, bfhi(P.w), a[7]);

// 16 lanes per node, lane-sub owns 8 dims; edge record {src, ew}; norm fused inline
__device__ __forceinline__ void gather_rows(
    const int* __restrict__ row_ptr, const uint2* __restrict__ cedge,
    const float* __restrict__ dinv, const uint4* __restrict__ xin,
    int n, int sub, float* a) {
  int beg = row_ptr[n], end = row_ptr[n + 1];
  int j = beg;
  for (; j + 4 <= end; j += 4) {
    uint2 e0 = cedge[j], e1 = cedge[j + 1], e2 = cedge[j + 2], e3 = cedge[j + 3];
    uint4 p0 = xin[(size_t)e0.x * 16 + sub];
    uint4 p1 = xin[(size_t)e1.x * 16 + sub];
    uint4 p2 = xin[(size_t)e2.x * 16 + sub];
    uint4 p3 = xin[(size_t)e3.x * 16 + sub];
    float w0 = dinv[e0.x] * __builtin_bit_cast(float, e0.y);
    float w1 = dinv[e1.x] * __builtin_bit_cast(float, e1.y);
    float w2 = dinv[e2.x] * __builtin_bit_cast(float, e2.y);
    float w3 = dinv[e3.x] * __builtin_bit_cast(float, e3.y);
    ACC8(p0, w0) ACC8(p1, w1) ACC8(p2, w2) ACC8(p3, w3)
  }
  for (; j < end; ++j) {
    uint2 e0 = cedge[j];
    uint4 p0 = xin[(size_t)e0.x * 16 + sub];
    float w0 = dinv[e0.x] * __builtin_bit_cast(float, e0.y);
    ACC8(p0, w0)
  }
}

// ---------------- 3-arm prep (R15 structure: GEMM tiles FIRST at full residency) ----------------
// blocks [0,NGEMM): content@W.T GEMM (FULL K=768, double-buffered) -> proj bf16
// blocks >= NGEMM, even: edge count + position capture (atomics)
// blocks >= NGEMM, odd:  x0 bf16 conversion (streaming)
__global__ __launch_bounds__(512) void prep_kernel(
    const int* __restrict__ dst, int* __restrict__ cnt, int* __restrict__ cpos,
    const float* __restrict__ uemb, const float* __restrict__ iemb,
    unsigned int* __restrict__ x0b,
    const float* __restrict__ W, const float* __restrict__ content,
    uint4* __restrict__ proj) {
  __shared__ unsigned short Asm[2][64 * 64];   // 16 KB (also epilogue transpose buf)
  __shared__ unsigned short Bsm[2][128 * 64];  // 32 KB

  int bid = blockIdx.x;
  int tid = threadIdx.x;

  if (bid >= NGEMM) {
    int sub = bid - NGEMM;
    int half = sub >> 1;
    if ((sub & 1) == 0) {
      int i = half * 512 + tid;
      for (; i < NE; i += 1024 * 512)
        cpos[i] = atomicAdd(&cnt[dst[i]], 1);
    } else {
      const size_t XT = (size_t)NN * D / 8;
      size_t t = (size_t)half * 512 + tid;
      for (; t < XT; t += (size_t)1024 * 512) {
        size_t f = t * 8;
        const float* p = (f < (size_t)NU * D) ? (uemb + f) : (iemb + (f - (size_t)NU * D));
        float4 a = *(const float4*)p;
        float4 b = *(const float4*)(p + 4);
        uint4 o;
        o.x = pack2bf(a.x, a.y); o.y = pack2bf(a.z, a.w);
        o.z = pack2bf(b.x, b.y); o.w = pack2bf(b.z, b.w);
        *(uint4*)(x0b + t * 4) = o;
      }
    }
    return;
  }

  // ---- GEMM arm: 64 items x 128 D, BK=64, 12 steps, double-buffered, 8 waves ----
  int w = tid >> 6, lane = tid & 63;
  int i0 = bid * 64;
  int lrow = lane & 15, kq = lane >> 4;

  f32x4 acc[4];
#pragma unroll
  for (int rt = 0; rt < 4; ++rt) acc[rt] = (f32x4){0.f, 0.f, 0.f, 0.f};

  int sr = tid >> 3, c8 = tid & 7;
  int arow_g = (i0 + sr < NI) ? (i0 + sr) : (NI - 1);
  const float* aG = content + (size_t)arow_g * CD + c8 * 8;
  const float* bG0 = W + (size_t)sr * CD + c8 * 8;
  const float* bG1 = W + (size_t)(sr + 64) * CD + c8 * 8;
  int aoff = (c8 * 16) ^ ((sr & 7) << 4);  // same swizzle for both B rows

  {
    float4 a0 = *(const float4*)(aG);
    float4 a1 = *(const float4*)(aG + 4);
    float4 p0 = *(const float4*)(bG0);
    float4 p1 = *(const float4*)(bG0 + 4);
    float4 q0 = *(const float4*)(bG1);
    float4 q1 = *(const float4*)(bG1 + 4);
    uint4 oa, ob, oc;
    oa.x = pack2bf(a0.x, a0.y); oa.y = pack2bf(a0.z, a0.w);
    oa.z = pack2bf(a1.x, a1.y); oa.w = pack2bf(a1.z, a1.w);
    ob.x = pack2bf(p0.x, p0.y); ob.y = pack2bf(p0.z, p0.w);
    ob.z = pack2bf(p1.x, p1.y); ob.w = pack2bf(p1.z, p1.w);
    oc.x = pack2bf(q0.x, q0.y); oc.y = pack2bf(q0.z, q0.w);
    oc.z = pack2bf(q1.x, q1.y); oc.w = pack2bf(q1.z, q1.w);
    *(uint4*)((char*)Asm[0] + sr * 128 + aoff) = oa;
    *(uint4*)((char*)Bsm[0] + sr * 128 + aoff) = ob;
    *(uint4*)((char*)Bsm[0] + (sr + 64) * 128 + aoff) = oc;
  }

  for (int kk = 0; kk < NK; ++kk) {
    __syncthreads();
    int cur = kk & 1, nxt = cur ^ 1;
    bool more = kk < NK - 1;
    float4 a0, a1, p0, p1, q0, q1;
    if (more) {
      int k0 = (kk + 1) * 64;
      a0 = *(const float4*)(aG + k0);
      a1 = *(const float4*)(aG + k0 + 4);
      p0 = *(const float4*)(bG0 + k0);
      p1 = *(const float4*)(bG0 + k0 + 4);
      q0 = *(const float4*)(bG1 + k0);
      q1 = *(const float4*)(bG1 + k0 + 4);
    }
#pragma unroll
    for (int ks = 0; ks < 2; ++ks) {
      int kbyte = ks * 64 + kq * 16;
      bf16x8 af[4], bfr;
#pragma unroll
      for (int rt = 0; rt < 4; ++rt) {
        int row = rt * 16 + lrow;
        af[rt] = *(const bf16x8*)((char*)Asm[cur] + row * 128 + (kbyte ^ ((row & 7) << 4)));
      }
      {
        int row = w * 16 + lrow;
        bfr = *(const bf16x8*)((char*)Bsm[cur] + row * 128 + (kbyte ^ ((row & 7) << 4)));
      }
#pragma unroll
      for (int rt = 0; rt < 4; ++rt)
        acc[rt] = __builtin_amdgcn_mfma_f32_16x16x32_bf16(af[rt], bfr, acc[rt], 0, 0, 0);
    }
    if (more) {
      uint4 oa, ob, oc;
      oa.x = pack2bf(a0.x, a0.y); oa.y = pack2bf(a0.z, a0.w);
      oa.z = pack2bf(a1.x, a1.y); oa.w = pack2bf(a1.z, a1.w);
      ob.x = pack2bf(p0.x, p0.y); ob.y = pack2bf(p0.z, p0.w);
      ob.z = pack2bf(p1.x, p1.y); ob.w = pack2bf(p1.z, p1.w);
      oc.x = pack2bf(q0.x, q0.y); oc.y = pack2bf(q0.z, q0.w);
      oc.z = pack2bf(q1.x, q1.y); oc.w = pack2bf(q1.z, q1.w);
      *(uint4*)((char*)Asm[nxt] + sr * 128 + aoff) = oa;
      *(uint4*)((char*)Bsm[nxt] + sr * 128 + aoff) = ob;
      *(uint4*)((char*)Bsm[nxt] + (sr + 64) * 128 + aoff) = oc;
    }
  }

  // epilogue: transpose acc through Asm (16 KB), store proj rows as bf16 uint4
  __syncthreads();
  unsigned short* T = (unsigned short*)Asm;  // [64][128]
  int dcol = w * 16 + lrow;
#pragma unroll
  for (int rt = 0; rt < 4; ++rt)
#pragma unroll
    for (int j = 0; j < 4; ++j)
      T[(rt * 16 + kq * 4 + j) * 128 + dcol] = f2bf(acc[rt][j]);
  __syncthreads();
#pragma unroll
  for (int u0 = 0; u0 < 2; ++u0) {
    int u = u0 * 512 + tid;
    int r = u >> 4, s = u & 15;
    int it = i0 + r;
    if (it < NI) proj[(size_t)it * 16 + s] = ((const uint4*)T)[u];
  }
}

// ---------------- prefix scan for CSR row_ptr ----------------

__global__ void scan_p1(const int* __restrict__ cnt, int* __restrict__ bsum) {
  __shared__ int s[256];
  int b = blockIdx.x;
  int i = b * 256 + threadIdx.x;
  s[threadIdx.x] = (i < NN) ? cnt[i] : 0;
  __syncthreads();
  for (int off = 128; off; off >>= 1) {
    if (threadIdx.x < off) s[threadIdx.x] += s[threadIdx.x + off];
    __syncthreads();
  }
  if (threadIdx.x == 0) bsum[b] = s[0];
}

__global__ __launch_bounds__(1024) void scan_p2(int* __restrict__ bsum, int nb) {
  __shared__ int s[1024];
  int t = threadIdx.x;
  int v = (t < nb) ? bsum[t] : 0;
  s[t] = v;
  __syncthreads();
  for (int off = 1; off < 1024; off <<= 1) {
    int u = (t >= off) ? s[t - off] : 0;
    __syncthreads();
    s[t] += u;
    __syncthreads();
  }
  if (t < nb) bsum[t] = s[t] - v;
}

__global__ void scan_p3(const int* __restrict__ cnt, const int* __restrict__ bsum,
                        int* __restrict__ row_ptr) {
  __shared__ int s[256];
  int b = blockIdx.x;
  int i = b * 256 + threadIdx.x;
  s[threadIdx.x] = (i < NN) ? cnt[i] : 0;
  __syncthreads();
  for (int off = 1; off < 256; off <<= 1) {
    int t = (threadIdx.x >= off) ? s[threadIdx.x - off] : 0;
    __syncthreads();
    s[threadIdx.x] += t;
    __syncthreads();
  }
  if (i < NN) row_ptr[i + 1] = bsum[b] + s[threadIdx.x];
  if (i == 0) row_ptr[0] = 0;
}

// ---------------- CSR fill: packed edge records {src, ew}, no atomics ----------------
__global__ void fill_kernel(const int* __restrict__ src, const int* __restrict__ dst,
                            const float* __restrict__ ew, const int* __restrict__ row_ptr,
                            const int* __restrict__ cpos, uint2* __restrict__ cedge) {
  int i = blockIdx.x * blockDim.x + threadIdx.x;
  int stride = gridDim.x * blockDim.x;
  for (; i < NE; i += stride) {
    int p = row_ptr[dst[i]] + cpos[i];
    uint2 e;
    e.x = (unsigned int)src[i];
    e.y = __builtin_bit_cast(unsigned int, ew[i]);
    cedge[p] = e;
  }
}

// ---------------- degree from CSR row sums + rsqrt ----------------
__global__ void degrow_kernel(const int* __restrict__ row_ptr, const uint2* __restrict__ cedge,
                              float* __restrict__ dinv) {
  int n = blockIdx.x * blockDim.x + threadIdx.x;
  if (n >= NN) return;
  int beg = row_ptr[n], end = row_ptr[n + 1];
  float s = 0.f;
  for (int p = beg; p < end; ++p) s += __builtin_bit_cast(float, cedge[p].y);
  dinv[n] = (s > 0.f) ? rsqrtf(s) : 0.f;
}

// ---------------- propagation layers (bf16 state; norm fused into gather) ----------------
__global__ __launch_bounds__(256) void gather_kernel(
    const int* __restrict__ row_ptr, const uint2* __restrict__ cedge,
    const float* __restrict__ dinv, const uint4* __restrict__ xin,
    uint4* __restrict__ yout) {
  int tid = threadIdx.x;
  int wv = tid >> 6, lane = tid & 63;
  int g = lane >> 4, sub = lane & 15;
  int n = blockIdx.x * 16 + wv * 4 + g;
  if (n >= NN) return;
  float sc = dinv[n];
  float a[8] = {0.f, 0.f, 0.f, 0.f, 0.f, 0.f, 0.f, 0.f};
  gather_rows(row_ptr, cedge, dinv, xin, n, sub, a);
  uint4 o;
  o.x = pack2bf(a[0] * sc, a[1] * sc);
  o.y = pack2bf(a[2] * sc, a[3] * sc);
  o.z = pack2bf(a[4] * sc, a[5] * sc);
  o.w = pack2bf(a[6] * sc, a[7] * sc);
  yout[(size_t)n * 16 + sub] = o;
}

// final layer: gather y3, OUT = 0.25*(x0+y1+y2+y3), fused align-MSE for item rows
__global__ __launch_bounds__(256) void final_kernel(
    const int* __restrict__ row_ptr, const uint2* __restrict__ cedge,
    const float* __restrict__ dinv, const uint4* __restrict__ x0b,
    const uint4* __restrict__ y1b, const uint4* __restrict__ y2b,
    const uint4* __restrict__ proj, float* __restrict__ OUT,
    float* __restrict__ partials) {
  __shared__ float wred[4];
  int tid = threadIdx.x;
  int wv = tid >> 6, lane = tid & 63;
  int g = lane >> 4, sub = lane & 15;
  int n = blockIdx.x * 16 + wv * 4 + g;
  if (n >= NN) return;
  // hoist independent stream loads before the gather loop (MLP)
  size_t r = (size_t)n * 16 + sub;
  uint4 q0 = x0b[r], q1 = y1b[r], q2 = y2b[r];
  float sc = dinv[n];
  float a[8] = {0.f, 0.f, 0.f, 0.f, 0.f, 0.f, 0.f, 0.f};
  gather_rows(row_ptr, cedge, dinv, y2b, n, sub, a);
  float v[8];
  v[0] = (bflo(q0.x) + bflo(q1.x) + bflo(q2.x) + a[0] * sc) * 0.25f;
  v[1] = (bfhi(q0.x) + bfhi(q1.x) + bfhi(q2.x) + a[1] * sc) * 0.25f;
  v[2] = (bflo(q0.y) + bflo(q1.y) + bflo(q2.y) + a[2] * sc) * 0.25f;
  v[3] = (bfhi(q0.y) + bfhi(q1.y) + bfhi(q2.y) + a[3] * sc) * 0.25f;
  v[4] = (bflo(q0.z) + bflo(q1.z) + bflo(q2.z) + a[4] * sc) * 0.25f;
  v[5] = (bfhi(q0.z) + bfhi(q1.z) + bfhi(q2.z) + a[5] * sc) * 0.25f;
  v[6] = (bflo(q0.w) + bflo(q1.w) + bflo(q2.w) + a[6] * sc) * 0.25f;
  v[7] = (bfhi(q0.w) + bfhi(q1.w) + bfhi(q2.w) + a[7] * sc) * 0.25f;
  float* op = OUT + (size_t)n * D + sub * 8;
#pragma unroll
  for (int k = 0; k < 8; ++k) op[k] = v[k];

  // item blocks are exactly blockIdx.x >= NU/16 (NU divisible by 16)
  if (blockIdx.x >= (NU / 16)) {
    uint4 pj = proj[(size_t)(n - NU) * 16 + sub];
    float d0 = v[0] - bflo(pj.x), d1 = v[1] - bfhi(pj.x);
    float d2 = v[2] - bflo(pj.y), d3 = v[3] - bfhi(pj.y);
    float d4 = v[4] - bflo(pj.z), d5 = v[5] - bfhi(pj.z);
    float d6 = v[6] - bflo(pj.w), d7 = v[7] - bfhi(pj.w);
    float m = d0 * d0 + d1 * d1 + d2 * d2 + d3 * d3 + d4 * d4 + d5 * d5 + d6 * d6 + d7 * d7;
    for (int off = 32; off; off >>= 1) m += __shfl_down(m, off);
    if (lane == 0) wred[wv] = m;
    __syncthreads();
    if (tid == 0)
      atomicAdd(&partials[blockIdx.x & 255], wred[0] + wred[1] + wred[2] + wred[3]);
  }
}

// ---------------- BPR + reg loss over batch (block-reduced atomics) ----------------
__global__ __launch_bounds__(256) void loss_batch(
    const int* __restrict__ bu, const int* __restrict__ bp, const int* __restrict__ bn,
    const float* __restrict__ OUT, float* __restrict__ accums) {
  __shared__ float wsp[4], wrg[4];
  int wv = threadIdx.x >> 6, lane = threadIdx.x & 63;
  int gw = blockIdx.x * 4 + wv;
  int nw = gridDim.x * 4;
  float lsp = 0.f, lrg = 0.f;
  for (int b = gw; b < BATCH; b += nw) {
    const float* u = OUT + (size_t)bu[b] * D;
    const float* ip = OUT + ((size_t)NU + bp[b]) * D;
    const float* in_ = OUT + ((size_t)NU + bn[b]) * D;
    float u0 = u[lane], u1 = u[lane + 64];
    float p0 = ip[lane], p1 = ip[lane + 64];
    float n0 = in_[lane], n1 = in_[lane + 64];
    float ps = u0 * p0 + u1 * p1;
    float ns = u0 * n0 + u1 * n1;
    float rg = u0 * u0 + u1 * u1 + p0 * p0 + p1 * p1 + n0 * n0 + n1 * n1;
    for (int off = 32; off; off >>= 1) {
      ps += __shfl_down(ps, off);
      ns += __shfl_down(ns, off);
      rg += __shfl_down(rg, off);
    }
    if (lane == 0) {
      float x = ns - ps;
      lsp += fmaxf(x, 0.f) + log1pf(expf(-fabsf(x)));
      lrg += rg;
    }
  }
  if (lane == 0) { wsp[wv] = lsp; wrg[wv] = lrg; }
  __syncthreads();
  if (threadIdx.x == 0) {
    atomicAdd(&accums[0], wsp[0] + wsp[1] + wsp[2] + wsp[3]);
    atomicAdd(&accums[1], wrg[0] + wrg[1] + wrg[2] + wrg[3]);
  }
}

__global__ void finalize_kernel(const float* __restrict__ accums,
                                const float* __restrict__ partials,
                                float* __restrict__ out0) {
  __shared__ float sm[4];
  int tid = threadIdx.x;
  float v = partials[tid];
  for (int off = 32; off; off >>= 1) v += __shfl_down(v, off);
  if ((tid & 63) == 0) sm[tid >> 6] = v;
  __syncthreads();
  if (tid == 0) {
    float align_sum = sm[0] + sm[1] + sm[2] + sm[3];
    float bpr = accums[0] / (float)BATCH;
    float reg = (accums[1] / (float)BATCH) * 1e-4f;
    float align = align_sum / (float)((size_t)NI * D);
    out0[0] = bpr + reg + 0.1f * align;
  }
}

// ---------------- launch ----------------
extern "C" void kernel_launch(void* const* d_in, const int* in_sizes, int n_in,
                              void* d_out, int out_size, void* d_ws, size_t ws_size,
                              hipStream_t stream) {
  const int* edge_index = (const int*)d_in[0];
  const float* ew = (const float*)d_in[1];
  const int* bu = (const int*)d_in[2];
  const int* bp = (const int*)d_in[3];
  const int* bn = (const int*)d_in[4];
  const float* content = (const float*)d_in[5];
  const float* uemb = (const float*)d_in[6];
  const float* iemb = (const float*)d_in[7];
  const float* W = (const float*)d_in[8];
  const int* src = edge_index;
  const int* dst = edge_index + NE;
  float* outf = (float*)d_out;
  float* OUT = outf + 1;  // [NN][D] fp32 (4B-aligned only!)

  char* ws = (char*)d_ws;
  size_t off = 0;
  auto alloc = [&](size_t bytes) {
    void* p = ws + off;
    off = alignup(off + bytes, 256);
    return p;
  };
  unsigned int* x0b = (unsigned int*)alloc((size_t)NN * 64 * 4);  // bf16 [NN][128]
  unsigned int* y1b = (unsigned int*)alloc((size_t)NN * 64 * 4);  // bf16 [NN][128]
  unsigned int* y2b = (unsigned int*)alloc((size_t)NN * 64 * 4);  // bf16 [NN][128]
  uint4* proj = (uint4*)alloc((size_t)NI * 16 * 16);              // bf16 [NI][128]
  float* dinv = (float*)alloc((size_t)NN * 4);
  int* cnt = (int*)alloc((size_t)NN * 4);
  int* row_ptr = (int*)alloc((size_t)(NN + 1) * 4);
  int NB = (NN + 255) / 256;
  int* bsum = (int*)alloc((size_t)NB * 4);
  int* cpos = (int*)alloc((size_t)NE * 4);
  uint2* cedge = (uint2*)alloc((size_t)NE * 8);
  float* accums = (float*)alloc(16 + 256 * 4);  // [0..3] accums, [4..259] mse partials
  float* partials = accums + 4;

  hipMemsetAsync(cnt, 0, (size_t)NN * 4, stream);
  hipMemsetAsync(accums, 0, 16 + 256 * 4, stream);

  prep_kernel<<<NGEMM + 2048, 512, 0, stream>>>(dst, cnt, cpos, uemb, iemb, x0b, W, content, proj);
  scan_p1<<<NB, 256, 0, stream>>>(cnt, bsum);
  scan_p2<<<1, 1024, 0, stream>>>(bsum, NB);
  scan_p3<<<NB, 256, 0, stream>>>(cnt, bsum, row_ptr);
  fill_kernel<<<2048, 256, 0, stream>>>(src, dst, ew, row_ptr, cpos, cedge);
  degrow_kernel<<<NB, 256, 0, stream>>>(row_ptr, cedge, dinv);

  int LB = (NN + 15) / 16;
  gather_kernel<<<LB, 256, 0, stream>>>(row_ptr, cedge, dinv, (const uint4*)x0b, (uint4*)y1b);
  gather_kernel<<<LB, 256, 0, stream>>>(row_ptr, cedge, dinv, (const uint4*)y1b, (uint4*)y2b);
  final_kernel<<<LB, 256, 0, stream>>>(row_ptr, cedge, dinv,
                                       (const uint4*)x0b, (const uint4*)y1b, (const uint4*)y2b,
                                       proj, OUT, partials);

  loss_batch<<<64, 256, 0, stream>>>(bu, bp, bn, OUT, accums);
  finalize_kernel<<<1, 256, 0, stream>>>(accums, partials, outf);
}